// Round 3
// 656.947 us; speedup vs baseline: 1.3903x; 1.3903x over previous
//
#include <hip/hip_runtime.h>

typedef __attribute__((ext_vector_type(4))) float f32x4;
typedef __attribute__((ext_vector_type(8))) __bf16 bf16x8;

#define COUT 512
#define NQ   65536
#define NP   16384
#define NSEG 4
#define SEGQ 16384
#define SEGP 4096
#define BN_EPS 1e-5f

// KNN chunking
#define NCHUNK 8
#define CHP    (SEGP / NCHUNK)   // 512 points per chunk
#define NCAND  (NCHUNK * 3)      // 24 merge candidates per query

// ---------------------------------------------------------------------------
// GEMM + BN(inference) + ReLU:  C[M][N] = relu((A@W + bias - mean)*rsqrt(var+eps)*gamma + beta)
// A: [M][K] f32 row-major, W: [K][N] f32 row-major. M%128==0, N%128==0, K%32==0.
// Block: 256 threads = 4 waves; tile 128x128, BK=32; wave computes 64x64 via
// 4x4 grid of 16x16x32 bf16 MFMAs.
// ---------------------------------------------------------------------------
#define BM 128
#define BNT 128
#define BK 32
#define LDSS 48   // padded LDS row stride in bf16 elems (96B, 16B-aligned rows)

__global__ __launch_bounds__(256)
void gemm_bn_relu_kernel(const float* __restrict__ A,
                         const float* __restrict__ W,
                         const float* __restrict__ bias,
                         const float* __restrict__ gamma,
                         const float* __restrict__ beta,
                         const float* __restrict__ mean,
                         const float* __restrict__ var,
                         float* __restrict__ C,
                         int M, int N, int K)
{
    __shared__ __bf16 As[BM][LDSS];   // [m][k]
    __shared__ __bf16 Bs[BNT][LDSS];  // [n][k]  (transposed tile of W)

    const int tid  = threadIdx.x;
    const int lane = tid & 63;
    const int wave = tid >> 6;
    const int quad = lane >> 4;
    const int l16  = lane & 15;
    const int wm   = (wave >> 1) * 64;   // wave's m offset in tile
    const int wn   = (wave & 1) * 64;    // wave's n offset in tile
    const int m0   = blockIdx.y * BM;
    const int n0   = blockIdx.x * BNT;

    // staging decomposition
    const int ar = tid >> 1;          // A tile row 0..127
    const int ak = (tid & 1) * 16;    // A tile k offset 0/16
    const int bk = tid & 31;          // W tile k row 0..31
    const int bn = (tid >> 5) * 16;   // W tile n offset 0..112

    f32x4 acc[4][4];
#pragma unroll
    for (int i = 0; i < 4; ++i)
#pragma unroll
        for (int j = 0; j < 4; ++j)
            acc[i][j] = (f32x4){0.f, 0.f, 0.f, 0.f};

    for (int k0 = 0; k0 < K; k0 += BK) {
        // ---- stage A tile (f32 -> bf16) ----
        {
            const float* src = A + (size_t)(m0 + ar) * K + (k0 + ak);
            f32x4 t0 = *(const f32x4*)(src + 0);
            f32x4 t1 = *(const f32x4*)(src + 4);
            f32x4 t2 = *(const f32x4*)(src + 8);
            f32x4 t3 = *(const f32x4*)(src + 12);
            __bf16 bt[16] __attribute__((aligned(16)));
#pragma unroll
            for (int i = 0; i < 4; ++i) {
                bt[i]      = (__bf16)t0[i];
                bt[4 + i]  = (__bf16)t1[i];
                bt[8 + i]  = (__bf16)t2[i];
                bt[12 + i] = (__bf16)t3[i];
            }
            *(uint4*)&As[ar][ak]     = *(uint4*)&bt[0];
            *(uint4*)&As[ar][ak + 8] = *(uint4*)&bt[8];
        }
        // ---- stage B tile (f32 -> bf16, transpose into [n][k]) ----
        {
            const float* src = W + (size_t)(k0 + bk) * N + (n0 + bn);
            f32x4 t0 = *(const f32x4*)(src + 0);
            f32x4 t1 = *(const f32x4*)(src + 4);
            f32x4 t2 = *(const f32x4*)(src + 8);
            f32x4 t3 = *(const f32x4*)(src + 12);
#pragma unroll
            for (int i = 0; i < 4; ++i) {
                Bs[bn + i][bk]      = (__bf16)t0[i];
                Bs[bn + 4 + i][bk]  = (__bf16)t1[i];
                Bs[bn + 8 + i][bk]  = (__bf16)t2[i];
                Bs[bn + 12 + i][bk] = (__bf16)t3[i];
            }
        }
        __syncthreads();

        // ---- one MFMA k-step (BK == 32 == MFMA K) ----
        bf16x8 af[4], bfr[4];
#pragma unroll
        for (int i = 0; i < 4; ++i)
            af[i] = *(const bf16x8*)&As[wm + i * 16 + l16][quad * 8];
#pragma unroll
        for (int j = 0; j < 4; ++j)
            bfr[j] = *(const bf16x8*)&Bs[wn + j * 16 + l16][quad * 8];
#pragma unroll
        for (int i = 0; i < 4; ++i)
#pragma unroll
            for (int j = 0; j < 4; ++j)
                acc[i][j] = __builtin_amdgcn_mfma_f32_16x16x32_bf16(
                    af[i], bfr[j], acc[i][j], 0, 0, 0);
        __syncthreads();
    }

    // ---- epilogue: BN + ReLU, store f32 ----
#pragma unroll
    for (int j = 0; j < 4; ++j) {
        const int col = n0 + wn + j * 16 + l16;
        const float al  = gamma[col] * rsqrtf(var[col] + BN_EPS);
        const float bt2 = (bias[col] - mean[col]) * al + beta[col];
#pragma unroll
        for (int i = 0; i < 4; ++i) {
            const int row = m0 + wm + i * 16 + quad * 4;
#pragma unroll
            for (int r = 0; r < 4; ++r) {
                float v = acc[i][j][r] * al + bt2;
                v = fmaxf(v, 0.f);
                C[(size_t)(row + r) * N + col] = v;
            }
        }
    }
}

// ---------------------------------------------------------------------------
// KNN top-3 pass 1, chunked for occupancy. VERBATIM clone of the passing
// baseline knn_kernel body, restricted to a 512-point chunk:
//   - px/py/pz separate LDS arrays, ps recomputed in-loop (identical ops)
//   - identical branchy strict-< insert (earliest index wins ties)
//   - 1D grid: blockIdx.x = query_block*8 + chunk
// Per-chunk top-3 is written to part_d/part_i; union of per-chunk top-3s
// contains the global top-3, and chunk-ordered merge preserves tie order.
// ---------------------------------------------------------------------------
__global__ __launch_bounds__(256)
void knn_part_kernel(const float* __restrict__ P1,
                     const float* __restrict__ P2,
                     float* __restrict__ part_d,
                     int* __restrict__ part_i)
{
    __shared__ float px[CHP], py[CHP], pz[CHP];

    const int bq    = blockIdx.x >> 3;              // query block 0..255
    const int chunk = blockIdx.x & (NCHUNK - 1);    // 0..7
    const int q     = bq * 256 + threadIdx.x;       // 0..65535
    const int s     = q >> 14;                      // segment (16384 q/seg)
    const float* P2s = P2 + ((size_t)s * SEGP + (size_t)chunk * CHP) * 3;

    for (int i = threadIdx.x; i < CHP; i += 256) {
        px[i] = P2s[i * 3 + 0];
        py[i] = P2s[i * 3 + 1];
        pz[i] = P2s[i * 3 + 2];
    }
    __syncthreads();

    const float qx = P1[q * 3 + 0];
    const float qy = P1[q * 3 + 1];
    const float qz = P1[q * 3 + 2];
    const float qs = __fadd_rn(__fadd_rn(__fmul_rn(qx, qx), __fmul_rn(qy, qy)),
                               __fmul_rn(qz, qz));

    float d0 = __builtin_inff(), d1 = __builtin_inff(), d2 = __builtin_inff();
    int   i0 = 0, i1 = 0, i2 = 0;
    const int jbase = chunk * CHP;

#pragma unroll 4
    for (int j = 0; j < CHP; ++j) {
        const float x = px[j], y = py[j], z = pz[j];
        const float ps  = __fadd_rn(__fadd_rn(__fmul_rn(x, x), __fmul_rn(y, y)),
                                    __fmul_rn(z, z));
        const float dot = __fadd_rn(__fadd_rn(__fmul_rn(qx, x), __fmul_rn(qy, y)),
                                    __fmul_rn(qz, z));
        float dd = __fsub_rn(__fadd_rn(qs, ps), __fadd_rn(dot, dot));
        dd = fmaxf(dd, 0.f);
        const int jj = jbase + j;
        if (dd < d2) {
            if (dd < d1) {
                d2 = d1; i2 = i1;
                if (dd < d0) { d1 = d0; i1 = i0; d0 = dd; i0 = jj; }
                else         { d1 = dd; i1 = jj; }
            } else { d2 = dd; i2 = jj; }
        }
    }

    float* pd = part_d + (size_t)q * NCAND + chunk * 3;
    int*   pi = part_i + (size_t)q * NCAND + chunk * 3;
    pd[0] = d0; pd[1] = d1; pd[2] = d2;
    pi[0] = i0; pi[1] = i1; pi[2] = i2;
}

// ---------------------------------------------------------------------------
// Pass 2: merge 24 candidates/query with the same verbatim branchy insert
// (candidates arrive in chunk order = index order, so strict-< preserves
// earliest-index tie-breaking). Scalar loads only. Weights verbatim baseline.
// ---------------------------------------------------------------------------
__global__ __launch_bounds__(256)
void knn_merge_kernel(const float* __restrict__ part_d,
                      const int* __restrict__ part_i,
                      int* __restrict__ out_idx,
                      float* __restrict__ out_w)
{
    const int q = blockIdx.x * 256 + threadIdx.x;
    const float* pd = part_d + (size_t)q * NCAND;
    const int*   pi = part_i + (size_t)q * NCAND;

    float d0 = __builtin_inff(), d1 = __builtin_inff(), d2 = __builtin_inff();
    int   i0 = 0, i1 = 0, i2 = 0;

#pragma unroll
    for (int k = 0; k < NCAND; ++k) {
        const float dd = pd[k];
        const int   jj = pi[k];
        if (dd < d2) {
            if (dd < d1) {
                d2 = d1; i2 = i1;
                if (dd < d0) { d1 = d0; i1 = i0; d0 = dd; i0 = jj; }
                else         { d1 = dd; i1 = jj; }
            } else { d2 = dd; i2 = jj; }
        }
    }

    const float r0 = 1.0f / (d0 + 1e-8f);
    const float r1 = 1.0f / (d1 + 1e-8f);
    const float r2 = 1.0f / (d2 + 1e-8f);
    const float rs = __fadd_rn(__fadd_rn(r0, r1), r2);
    out_idx[q * 3 + 0] = i0;
    out_idx[q * 3 + 1] = i1;
    out_idx[q * 3 + 2] = i2;
    out_w[q * 3 + 0] = r0 / rs;
    out_w[q * 3 + 1] = r1 / rs;
    out_w[q * 3 + 2] = r2 / rs;
}

// ---------------------------------------------------------------------------
// out[q][c] += w0*x2[seg_base+i0][c] + w1*... + w2*...   (out holds x1 already)
// 128 threads per query (float4 per thread over 512 channels).
// ---------------------------------------------------------------------------
__global__ __launch_bounds__(256)
void interp_add_kernel(const float* __restrict__ x2,
                       const int* __restrict__ idx,
                       const float* __restrict__ w,
                       float* __restrict__ out)
{
    const int t = blockIdx.x * 256 + threadIdx.x;
    const int q = t >> 7;
    const int c = (t & 127) << 2;
    const int s = q >> 14;
    const int* id = idx + q * 3;
    const float* ww = w + q * 3;
    const size_t segbase = (size_t)(s * SEGP) * COUT;

    const f32x4 f0 = *(const f32x4*)(x2 + segbase + (size_t)id[0] * COUT + c);
    const f32x4 f1 = *(const f32x4*)(x2 + segbase + (size_t)id[1] * COUT + c);
    const f32x4 f2 = *(const f32x4*)(x2 + segbase + (size_t)id[2] * COUT + c);

    f32x4 o = *(const f32x4*)(out + (size_t)q * COUT + c);
    o = o + f0 * ww[0] + f1 * ww[1] + f2 * ww[2];
    *(f32x4*)(out + (size_t)q * COUT + c) = o;
}

// ---------------------------------------------------------------------------
// Workspace footprint IDENTICAL to the passing baseline (35.1 MB):
//   [0, 32MB)   x2 (16384x512 f32) -- transiently holds KNN partials
//               (part_d 6.29MB | part_i 6.29MB) until gemm-x2 runs
//   [32MB, ..)  idb (65536x3 i32), wb (65536x3 f32)
// Single-stream order guarantees no hazard:
//   gemm-x1 -> knn_part(write partials) -> knn_merge(read partials, write
//   idb/wb) -> gemm-x2(overwrite partials with x2) -> interp_add.
// ---------------------------------------------------------------------------
extern "C" void kernel_launch(void* const* d_in, const int* in_sizes, int n_in,
                              void* d_out, int out_size, void* d_ws, size_t ws_size,
                              hipStream_t stream)
{
    const float* point_1 = (const float*)d_in[0];
    const float* feat_1  = (const float*)d_in[1];
    const float* point_2 = (const float*)d_in[2];
    const float* feat_2  = (const float*)d_in[3];
    const float* W1  = (const float*)d_in[4];
    const float* b1  = (const float*)d_in[5];
    const float* g1  = (const float*)d_in[6];
    const float* be1 = (const float*)d_in[7];
    const float* m1  = (const float*)d_in[8];
    const float* v1  = (const float*)d_in[9];
    const float* W2  = (const float*)d_in[10];
    const float* b2  = (const float*)d_in[11];
    const float* g2  = (const float*)d_in[12];
    const float* be2 = (const float*)d_in[13];
    const float* m2  = (const float*)d_in[14];
    const float* v2  = (const float*)d_in[15];
    float* out = (float*)d_out;

    char* wsp = (char*)d_ws;
    float* x2  = (float*)wsp;                 wsp += (size_t)NP * COUT * 4;   // 32MB
    int*   idb = (int*)wsp;                   wsp += (size_t)NQ * 3 * 4;      // 768KB
    float* wb  = (float*)wsp;                                                 // 768KB
    // KNN partials overlaid inside the x2 slot (dead before gemm-x2 writes)
    float* pdb = (float*)d_ws;                                                // 6.29MB
    int*   pib = (int*)((char*)d_ws + (size_t)NQ * NCAND * 4);                // 6.29MB

    // x1 -> out
    gemm_bn_relu_kernel<<<dim3(COUT / BNT, NQ / BM), 256, 0, stream>>>(
        feat_1, W1, b1, g1, be1, m1, v1, out, NQ, COUT, 512);
    // knn pass 1: per-chunk partial top-3 (into x2 slot, consumed before x2 written)
    knn_part_kernel<<<(NQ / 256) * NCHUNK, 256, 0, stream>>>(
        point_1, point_2, pdb, pib);
    // knn pass 2: merge + weights
    knn_merge_kernel<<<NQ / 256, 256, 0, stream>>>(pdb, pib, idb, wb);
    // x2 -> ws (overwrites consumed partials)
    gemm_bn_relu_kernel<<<dim3(COUT / BNT, NP / BM), 256, 0, stream>>>(
        feat_2, W2, b2, g2, be2, m2, v2, x2, NP, COUT, 1024);
    // gather-interp + residual
    interp_add_kernel<<<(NQ * (COUT / 4)) / 256, 256, 0, stream>>>(x2, idb, wb, out);
}